// Round 1
// baseline (196.746 us; speedup 1.0000x reference)
//
#include <hip/hip_runtime.h>
#include <math.h>

// ---------------------------------------------------------------------------
// QFCModel: avgpool(6) -> linear(16->4) -> 4-qubit circuit -> linear(4->4) -> BN
//
// Circuit collapse: final_state = U_var @ (RX(z0)⊗RX(z1)⊗RX(z2)⊗RX(z3))|0>
//   product state amp_k = (-i)^popcount(k) * r_k,  r_k real product of cos/sin
//   V = U_var * diag((-i)^popcount(k))  (precomputed once from qparams)
//   probs_i = (Vr r)_i^2 + (Vi r)_i^2
//   out_j   = cls_b[j] + sum_i W2[j,i] probs_i,  W2[j,i] = sum_w cls_w[j,w]*sign_w(i)
// ---------------------------------------------------------------------------

#define BTOT 32768

// ---- kernel 1: build V (16x16 complex as Vr/Vi) and W2 (4x16) -------------
__global__ __launch_bounds__(64) void prep_kernel(
    const float* __restrict__ qparams, const float* __restrict__ cls_w,
    float* __restrict__ Vr, float* __restrict__ Vi, float* __restrict__ W2)
{
    int t = threadIdx.x;
    if (t < 16) {
        // simulate variational layers on basis state e_t -> column t of U
        float pr[16], pi[16];
        #pragma unroll
        for (int i = 0; i < 16; ++i) { pr[i] = (i == t) ? 1.f : 0.f; pi[i] = 0.f; }
        for (int layer = 0; layer < 3; ++layer) {
            for (int w = 0; w < 4; ++w) {
                const float* qp = qparams + (layer * 4 + w) * 3;
                float phi = qp[0], th = qp[1], om = qp[2];
                float c, s, ca, sa, cd, sd;
                sincosf(0.5f * th, &s, &c);
                sincosf(0.5f * (phi + om), &sa, &ca);
                sincosf(0.5f * (phi - om), &sd, &cd);
                // PennyLane Rot(phi,theta,omega) = RZ(om) RY(th) RZ(phi)
                float u00r =  c * ca, u00i = -c * sa;
                float u01r = -s * cd, u01i = -s * sd;
                float u10r =  s * cd, u10i = -s * sd;
                float u11r =  c * ca, u11i =  c * sa;
                int m = 8 >> w;   // wire 0 = MSB of 4-bit index
                for (int idx = 0; idx < 16; ++idx) {
                    if (idx & m) continue;
                    int i1 = idx | m;
                    float ar = pr[idx], ai = pi[idx], br = pr[i1], bi = pi[i1];
                    pr[idx] = u00r*ar - u00i*ai + u01r*br - u01i*bi;
                    pi[idx] = u00r*ai + u00i*ar + u01r*bi + u01i*br;
                    pr[i1]  = u10r*ar - u10i*ai + u11r*br - u11i*bi;
                    pi[i1]  = u10r*ai + u10i*ar + u11r*bi + u11i*br;
                }
            }
            // CNOT ladder: control w, target w+1  (swap target bit where control set)
            for (int w = 0; w < 3; ++w) {
                int mc = 8 >> w, mt = 8 >> (w + 1);
                for (int idx = 0; idx < 16; ++idx) {
                    if ((idx & mc) && !(idx & mt)) {
                        int i1 = idx | mt;
                        float tr = pr[idx], ti = pi[idx];
                        pr[idx] = pr[i1]; pi[idx] = pi[i1];
                        pr[i1] = tr;      pi[i1] = ti;
                    }
                }
            }
        }
        // fold (-i)^popcount(column) into the column
        int p = __popc(t) & 3;
        #pragma unroll
        for (int i = 0; i < 16; ++i) {
            float re = pr[i], im = pi[i], vr, vi;
            if (p == 0)      { vr = re;  vi = im;  }
            else if (p == 1) { vr = im;  vi = -re; }
            else if (p == 2) { vr = -re; vi = -im; }
            else             { vr = -im; vi = re;  }
            Vr[i * 16 + t] = vr;
            Vi[i * 16 + t] = vi;
        }
    }
    // W2[j][i] = sum_w cls_w[j][w] * (bit_w(i) ? -1 : +1)
    {
        int j = t >> 4, i = t & 15;
        float acc = 0.f;
        #pragma unroll
        for (int w = 0; w < 4; ++w) {
            float sgn = (i & (8 >> w)) ? -1.f : 1.f;
            acc += cls_w[j * 4 + w] * sgn;
        }
        W2[j * 16 + i] = acc;
    }
}

// ---- kernel 2: 6x6 average pool, thread per (sample, cell) ----------------
__global__ __launch_bounds__(256) void pool_kernel(
    const float* __restrict__ x, float* __restrict__ pooled)
{
    int t = blockIdx.x * 256 + threadIdx.x;       // 524288 threads
    int s = t >> 4, cell = t & 15;
    const float* base = x + (size_t)s * 784 + (size_t)((cell >> 2) * 6) * 28 + (cell & 3) * 6;
    float sum = 0.f;
    #pragma unroll
    for (int r = 0; r < 6; ++r) {
        const float* rp = base + r * 28;
        sum += (rp[0] + rp[1]) + (rp[2] + rp[3]) + (rp[4] + rp[5]);
    }
    pooled[t] = sum * (1.f / 36.f);
}

// ---- kernel 3: encode + circuit + classifier, thread per sample -----------
__global__ __launch_bounds__(128) void circuit_kernel(
    const float* __restrict__ pooled,
    const float* __restrict__ enc_w, const float* __restrict__ enc_b,
    const float* __restrict__ Vr, const float* __restrict__ Vi,
    const float* __restrict__ W2, const float* __restrict__ cls_b,
    float* __restrict__ preBN, float* __restrict__ sums)
{
    int s = blockIdx.x * 128 + threadIdx.x;
    float pv[16];
    const float4* pp = (const float4*)(pooled + (size_t)s * 16);
    #pragma unroll
    for (int q = 0; q < 4; ++q) {
        float4 v = pp[q];
        pv[q*4+0] = v.x; pv[q*4+1] = v.y; pv[q*4+2] = v.z; pv[q*4+3] = v.w;
    }
    // z = enc_w @ pooled + enc_b ; angles/2
    float cz[4], szn[4];
    #pragma unroll
    for (int j = 0; j < 4; ++j) {
        float z = enc_b[j];
        #pragma unroll
        for (int k = 0; k < 16; ++k) z += enc_w[j * 16 + k] * pv[k];
        sincosf(0.5f * z, &szn[j], &cz[j]);
    }
    // r_k = prod_w (bit_w(k) ? sin : cos)
    float a01[4] = {cz[0]*cz[1], cz[0]*szn[1], szn[0]*cz[1], szn[0]*szn[1]};
    float a23[4] = {cz[2]*cz[3], cz[2]*szn[3], szn[2]*cz[3], szn[2]*szn[3]};
    float r[16];
    #pragma unroll
    for (int k = 0; k < 16; ++k) r[k] = a01[k >> 2] * a23[k & 3];
    // probs -> out (V, W2 are wave-uniform -> scalar loads)
    float out[4] = {cls_b[0], cls_b[1], cls_b[2], cls_b[3]};
    #pragma unroll
    for (int i = 0; i < 16; ++i) {
        float ar = 0.f, ai = 0.f;
        #pragma unroll
        for (int k = 0; k < 16; ++k) {
            ar += Vr[i * 16 + k] * r[k];
            ai += Vi[i * 16 + k] * r[k];
        }
        float p = ar * ar + ai * ai;
        #pragma unroll
        for (int j = 0; j < 4; ++j) out[j] += W2[j * 16 + i] * p;
    }
    ((float4*)preBN)[s] = make_float4(out[0], out[1], out[2], out[3]);

    // block reduction of sums / sumsqs for batch-norm stats
    float v[8] = {out[0], out[1], out[2], out[3],
                  out[0]*out[0], out[1]*out[1], out[2]*out[2], out[3]*out[3]};
    #pragma unroll
    for (int off = 32; off > 0; off >>= 1) {
        #pragma unroll
        for (int m = 0; m < 8; ++m) v[m] += __shfl_down(v[m], off, 64);
    }
    __shared__ float red[2][8];
    int wave = threadIdx.x >> 6, lane = threadIdx.x & 63;
    if (lane == 0) {
        #pragma unroll
        for (int m = 0; m < 8; ++m) red[wave][m] = v[m];
    }
    __syncthreads();
    if (threadIdx.x < 8) atomicAdd(&sums[threadIdx.x], red[0][threadIdx.x] + red[1][threadIdx.x]);
}

// ---- kernel 4: batch-norm (training mode, biased var) in place ------------
__global__ __launch_bounds__(128) void bn_kernel(
    const float* __restrict__ sums,
    const float* __restrict__ gamma, const float* __restrict__ beta,
    float* __restrict__ out)
{
    int s = blockIdx.x * 128 + threadIdx.x;
    const float invB = 1.f / (float)BTOT;
    float4 v = ((const float4*)out)[s];
    float o[4] = {v.x, v.y, v.z, v.w};
    #pragma unroll
    for (int j = 0; j < 4; ++j) {
        float mu   = sums[j] * invB;
        float var  = sums[4 + j] * invB - mu * mu;
        float rstd = rsqrtf(var + 1e-5f);
        o[j] = (o[j] - mu) * rstd * gamma[j] + beta[j];
    }
    ((float4*)out)[s] = make_float4(o[0], o[1], o[2], o[3]);
}

extern "C" void kernel_launch(void* const* d_in, const int* in_sizes, int n_in,
                              void* d_out, int out_size, void* d_ws, size_t ws_size,
                              hipStream_t stream)
{
    const float* x        = (const float*)d_in[0];
    const float* enc_w    = (const float*)d_in[1];
    const float* enc_b    = (const float*)d_in[2];
    const float* qparams  = (const float*)d_in[3];
    const float* cls_w    = (const float*)d_in[4];
    const float* cls_b    = (const float*)d_in[5];
    const float* bn_gamma = (const float*)d_in[6];
    const float* bn_beta  = (const float*)d_in[7];

    float* ws     = (float*)d_ws;
    float* Vr     = ws;          // 256 floats
    float* Vi     = ws + 256;    // 256 floats
    float* W2     = ws + 512;    // 64 floats
    float* sums   = ws + 576;    // 8 floats (atomics)
    float* pooled = ws + 1024;   // 524288 floats (2 MB)
    float* outp   = (float*)d_out;  // doubles as pre-BN scratch (exact size match)

    prep_kernel<<<1, 64, 0, stream>>>(qparams, cls_w, Vr, Vi, W2);
    pool_kernel<<<2048, 256, 0, stream>>>(x, pooled);
    hipMemsetAsync(sums, 0, 8 * sizeof(float), stream);
    circuit_kernel<<<256, 128, 0, stream>>>(pooled, enc_w, enc_b, Vr, Vi, W2, cls_b, outp, sums);
    bn_kernel<<<256, 128, 0, stream>>>(sums, bn_gamma, bn_beta, outp);
}

// Round 2
// 185.607 us; speedup vs baseline: 1.0600x; 1.0600x over previous
//
#include <hip/hip_runtime.h>
#include <math.h>

// ---------------------------------------------------------------------------
// QFCModel fused: avgpool(6) -> linear(16->4) -> 4-qubit circuit -> linear -> BN
//
// Circuit collapse: state = U_var @ (RX(z0)⊗..⊗RX(z3))|0>
//   amp_k = (-i)^popcount(k) * r_k, r real product of cos/sin(z/2)
//   V = U_var * diag((-i)^popc)  -> probs_i = (Vr r)_i^2 + (Vi r)_i^2
//   out_j = cls_b[j] + sum_i W2[j,i] probs_i, W2[j,i] = sum_w cls_w[j,w]*sign_w(i)
//
// Layout: 4 threads per sample (t = s*4 + rg). Thread pools rows rg*6..rg*6+5
// (6x float4 per row, 16B-aligned), partial-encodes, shfl_xor-combines z,
// computes 4 of 16 matvec rows against LDS-resident V^T, shfl_xor-combines out.
// V/W2 built once per block by wave 0 (hides behind pooling loads).
// ---------------------------------------------------------------------------

#define BTOT 32768

__global__ __launch_bounds__(256) void fused_kernel(
    const float* __restrict__ x,
    const float* __restrict__ enc_w, const float* __restrict__ enc_b,
    const float* __restrict__ qparams,
    const float* __restrict__ cls_w, const float* __restrict__ cls_b,
    float* __restrict__ preBN, float* __restrict__ sums)
{
    __shared__ float sVrT[256];   // sVrT[k*16 + i] = V[i][k]
    __shared__ float sViT[256];
    __shared__ float sW2[64];     // sW2[j*16 + i]
    __shared__ float red[4][8];

    const int tid = threadIdx.x;

    // ---- prep: wave 0 builds W2 and V into LDS -------------------------
    if (tid < 64) {
        int j = tid >> 4, i = tid & 15;
        float acc = 0.f;
        #pragma unroll
        for (int w = 0; w < 4; ++w)
            acc += cls_w[j * 4 + w] * ((i & (8 >> w)) ? -1.f : 1.f);
        sW2[j * 16 + i] = acc;
    }
    if (tid < 16) {
        // simulate variational layers on basis state e_tid -> column tid of U
        float pr[16], pi[16];
        #pragma unroll
        for (int i = 0; i < 16; ++i) { pr[i] = (i == tid) ? 1.f : 0.f; pi[i] = 0.f; }
        for (int layer = 0; layer < 3; ++layer) {
            for (int w = 0; w < 4; ++w) {
                const float* qp = qparams + (layer * 4 + w) * 3;
                float phi = qp[0], th = qp[1], om = qp[2];
                float c, s, ca, sa, cd, sd;
                sincosf(0.5f * th, &s, &c);
                sincosf(0.5f * (phi + om), &sa, &ca);
                sincosf(0.5f * (phi - om), &sd, &cd);
                float u00r =  c * ca, u00i = -c * sa;
                float u01r = -s * cd, u01i = -s * sd;
                float u10r =  s * cd, u10i = -s * sd;
                float u11r =  c * ca, u11i =  c * sa;
                int m = 8 >> w;   // wire 0 = MSB
                for (int idx = 0; idx < 16; ++idx) {
                    if (idx & m) continue;
                    int i1 = idx | m;
                    float ar = pr[idx], ai = pi[idx], br = pr[i1], bi = pi[i1];
                    pr[idx] = u00r*ar - u00i*ai + u01r*br - u01i*bi;
                    pi[idx] = u00r*ai + u00i*ar + u01r*bi + u01i*br;
                    pr[i1]  = u10r*ar - u10i*ai + u11r*br - u11i*bi;
                    pi[i1]  = u10r*ai + u10i*ar + u11r*bi + u11i*br;
                }
            }
            for (int w = 0; w < 3; ++w) {  // CNOT ladder
                int mc = 8 >> w, mt = 8 >> (w + 1);
                for (int idx = 0; idx < 16; ++idx) {
                    if ((idx & mc) && !(idx & mt)) {
                        int i1 = idx | mt;
                        float tr = pr[idx], ti = pi[idx];
                        pr[idx] = pr[i1]; pi[idx] = pi[i1];
                        pr[i1] = tr;      pi[i1] = ti;
                    }
                }
            }
        }
        // fold (-i)^popcount(column tid); store transposed
        int p = __popc(tid) & 3;
        #pragma unroll
        for (int i = 0; i < 16; ++i) {
            float re = pr[i], im = pi[i], vr, vi;
            if (p == 0)      { vr = re;  vi = im;  }
            else if (p == 1) { vr = im;  vi = -re; }
            else if (p == 2) { vr = -re; vi = -im; }
            else             { vr = -im; vi = re;  }
            sVrT[tid * 16 + i] = vr;
            sViT[tid * 16 + i] = vi;
        }
    }

    // ---- pooling: thread handles (sample s, rowgroup rg) ----------------
    const int tg = blockIdx.x * 256 + tid;   // 131072 threads total
    const int s  = tg >> 2, rg = tg & 3;
    const float* base = x + (size_t)s * 784 + rg * 6 * 28;
    float p0 = 0.f, p1 = 0.f, p2 = 0.f, p3 = 0.f;
    #pragma unroll
    for (int r = 0; r < 6; ++r) {
        const float4* rp = (const float4*)(base + r * 28);   // 16B-aligned
        float4 v0 = rp[0], v1 = rp[1], v2 = rp[2], v3 = rp[3], v4 = rp[4], v5 = rp[5];
        p0 += (v0.x + v0.y) + (v0.z + v0.w) + (v1.x + v1.y);
        p1 += (v1.z + v1.w) + (v2.x + v2.y) + (v2.z + v2.w);
        p2 += (v3.x + v3.y) + (v3.z + v3.w) + (v4.x + v4.y);
        p3 += (v4.z + v4.w) + (v5.x + v5.y) + (v5.z + v5.w);
    }
    const float inv36 = 1.f / 36.f;
    float pv[4] = {p0 * inv36, p1 * inv36, p2 * inv36, p3 * inv36};

    // ---- encode: partial z over this thread's 4 pooled cells ------------
    float z[4];
    #pragma unroll
    for (int j = 0; j < 4; ++j) {
        float acc = 0.f;
        #pragma unroll
        for (int c = 0; c < 4; ++c) acc += enc_w[j * 16 + rg * 4 + c] * pv[c];
        z[j] = acc;
    }
    #pragma unroll
    for (int j = 0; j < 4; ++j) {
        z[j] += __shfl_xor(z[j], 1, 64);
        z[j] += __shfl_xor(z[j], 2, 64);
        z[j] += enc_b[j];
    }

    // ---- product state r_k ----------------------------------------------
    float cz[4], sz[4];
    #pragma unroll
    for (int j = 0; j < 4; ++j) sincosf(0.5f * z[j], &sz[j], &cz[j]);
    float a01[4] = {cz[0]*cz[1], cz[0]*sz[1], sz[0]*cz[1], sz[0]*sz[1]};
    float a23[4] = {cz[2]*cz[3], cz[2]*sz[3], sz[2]*cz[3], sz[2]*sz[3]};
    float rv[16];
    #pragma unroll
    for (int k = 0; k < 16; ++k) rv[k] = a01[k >> 2] * a23[k & 3];

    __syncthreads();   // V/W2 ready in LDS

    // ---- matvec rows i = rg*4 .. rg*4+3 ---------------------------------
    float arA[4] = {0,0,0,0}, aiA[4] = {0,0,0,0};
    #pragma unroll
    for (int k = 0; k < 16; ++k) {
        float4 vr4 = *(const float4*)&sVrT[k * 16 + rg * 4];
        float4 vi4 = *(const float4*)&sViT[k * 16 + rg * 4];
        float rk = rv[k];
        arA[0] += vr4.x * rk; arA[1] += vr4.y * rk; arA[2] += vr4.z * rk; arA[3] += vr4.w * rk;
        aiA[0] += vi4.x * rk; aiA[1] += vi4.y * rk; aiA[2] += vi4.z * rk; aiA[3] += vi4.w * rk;
    }
    float out[4] = {0, 0, 0, 0};
    #pragma unroll
    for (int m = 0; m < 4; ++m) {
        float pp = arA[m] * arA[m] + aiA[m] * aiA[m];
        #pragma unroll
        for (int j = 0; j < 4; ++j) out[j] += sW2[j * 16 + rg * 4 + m] * pp;
    }
    #pragma unroll
    for (int j = 0; j < 4; ++j) {
        out[j] += __shfl_xor(out[j], 1, 64);
        out[j] += __shfl_xor(out[j], 2, 64);
        out[j] += cls_b[j];
    }
    if (rg == 0) ((float4*)preBN)[s] = make_float4(out[0], out[1], out[2], out[3]);

    // ---- BN statistics (count each sample once: rg==0 lanes) -------------
    float w = (rg == 0) ? 1.f : 0.f;
    float v8[8] = {out[0]*w, out[1]*w, out[2]*w, out[3]*w,
                   out[0]*out[0]*w, out[1]*out[1]*w, out[2]*out[2]*w, out[3]*out[3]*w};
    #pragma unroll
    for (int off = 32; off > 0; off >>= 1) {
        #pragma unroll
        for (int m = 0; m < 8; ++m) v8[m] += __shfl_down(v8[m], off, 64);
    }
    int wave = tid >> 6, lane = tid & 63;
    if (lane == 0) {
        #pragma unroll
        for (int m = 0; m < 8; ++m) red[wave][m] = v8[m];
    }
    __syncthreads();
    if (tid < 8)
        atomicAdd(&sums[tid], red[0][tid] + red[1][tid] + red[2][tid] + red[3][tid]);
}

// ---- batch-norm (training mode, biased var) in place ----------------------
__global__ __launch_bounds__(256) void bn_kernel(
    const float* __restrict__ sums,
    const float* __restrict__ gamma, const float* __restrict__ beta,
    float* __restrict__ out)
{
    int s = blockIdx.x * 256 + threadIdx.x;
    const float invB = 1.f / (float)BTOT;
    float4 v = ((const float4*)out)[s];
    float o[4] = {v.x, v.y, v.z, v.w};
    #pragma unroll
    for (int j = 0; j < 4; ++j) {
        float mu   = sums[j] * invB;
        float var  = sums[4 + j] * invB - mu * mu;
        float rstd = rsqrtf(var + 1e-5f);
        o[j] = (o[j] - mu) * rstd * gamma[j] + beta[j];
    }
    ((float4*)out)[s] = make_float4(o[0], o[1], o[2], o[3]);
}

extern "C" void kernel_launch(void* const* d_in, const int* in_sizes, int n_in,
                              void* d_out, int out_size, void* d_ws, size_t ws_size,
                              hipStream_t stream)
{
    const float* x        = (const float*)d_in[0];
    const float* enc_w    = (const float*)d_in[1];
    const float* enc_b    = (const float*)d_in[2];
    const float* qparams  = (const float*)d_in[3];
    const float* cls_w    = (const float*)d_in[4];
    const float* cls_b    = (const float*)d_in[5];
    const float* bn_gamma = (const float*)d_in[6];
    const float* bn_beta  = (const float*)d_in[7];

    float* sums = (float*)d_ws;          // 8 floats (atomic accumulators)
    float* outp = (float*)d_out;         // pre-BN scratch == final out

    hipMemsetAsync(sums, 0, 8 * sizeof(float), stream);
    fused_kernel<<<512, 256, 0, stream>>>(x, enc_w, enc_b, qparams, cls_w, cls_b,
                                          outp, sums);
    bn_kernel<<<128, 256, 0, stream>>>(sums, bn_gamma, bn_beta, outp);
}